// Round 2
// baseline (571.276 us; speedup 1.0000x reference)
//
#include <hip/hip_runtime.h>
#include <math.h>

// AnomalyAttention: B=4, H=8, L=S=1024, E=D=64, fp32 in/out.
// out = [ V (B,L,H,D) | series (B,H,L,S) | prior (B,H,L,S) | sig (B,H,L,S) ]
//
// Strategy: no fp32 MFMA on CDNA4 -> 3-term split-bf16 MFMA (hi*hi + lo*hi +
// hi*lo, ~1e-4 rel err) for both QK^T and PV. Everything else is write-bound
// (411 MB of outputs -> ~65 us floor at 6.3 TB/s).

typedef __attribute__((ext_vector_type(8))) short short8;   // 8 bf16 (4 VGPR)
typedef __attribute__((ext_vector_type(4))) float f32x4;

constexpr int Bc = 4, Lc = 1024, Hc = 8, Ec = 64, Dc = 64, Sc = 1024;

constexpr long OFF_V      = 0;
constexpr long OFF_SERIES = (long)Bc * Lc * Hc * Dc;                 // 2097152
constexpr long OFF_PRIOR  = OFF_SERIES + (long)Bc * Hc * Lc * Sc;    // 35651584
constexpr long OFF_SIG    = OFF_PRIOR  + (long)Bc * Hc * Lc * Sc;    // 69206016

constexpr long KELEMS = (long)Bc * Lc * Hc * Ec;   // 2097152 elements

#define LOG2E        1.4426950408889634f
#define LOG2_3       1.5849625007211562f
#define INV_SQRT_2PI 0.3989422804014327f
#define HALF_LOG2E   0.7213475204444817f
#define FIVE_LOG2E   7.213475204444817f

__device__ __forceinline__ unsigned short f2bf(float x) {   // RTNE f32->bf16
    unsigned int u = __float_as_uint(x);
    return (unsigned short)((u + 0x7fffu + ((u >> 16) & 1u)) >> 16);
}
__device__ __forceinline__ float bf2f(unsigned short h) {
    return __uint_as_float(((unsigned int)h) << 16);
}
__device__ __forceinline__ void split8(const float* v, short8& hi, short8& lo) {
    #pragma unroll
    for (int j = 0; j < 8; ++j) {
        unsigned short hh = f2bf(v[j]);
        hi[j] = (short)hh;
        lo[j] = (short)f2bf(v[j] - bf2f(hh));
    }
}

// ---------------------------------------------------------------------------
// K prep: [b,s,h,e] f32 -> [b,h,s,e] bf16 hi + lo. 1 float4 per thread.
// ---------------------------------------------------------------------------
__global__ __launch_bounds__(256)
void k_prep(const float* __restrict__ kp, unsigned short* __restrict__ khi,
            unsigned short* __restrict__ klo)
{
    const int i = blockIdx.x * 256 + threadIdx.x;        // 0..524287
    const int e4 = i & 15, h = (i >> 4) & 7, s = (i >> 7) & 1023, b = i >> 17;
    const float4 v = reinterpret_cast<const float4*>(kp)[((b * Lc + s) * Hc + h) * 16 + e4];
    const unsigned short h0 = f2bf(v.x), h1 = f2bf(v.y), h2 = f2bf(v.z), h3 = f2bf(v.w);
    uint2 hi, lo;
    hi.x = (unsigned)h0 | ((unsigned)h1 << 16);
    hi.y = (unsigned)h2 | ((unsigned)h3 << 16);
    lo.x = (unsigned)f2bf(v.x - bf2f(h0)) | ((unsigned)f2bf(v.y - bf2f(h1)) << 16);
    lo.y = (unsigned)f2bf(v.z - bf2f(h2)) | ((unsigned)f2bf(v.w - bf2f(h3)) << 16);
    const long dst = ((long)(b * Hc + h) * Lc + s) * 16 + e4;   // uint2 units
    reinterpret_cast<uint2*>(khi)[dst] = hi;
    reinterpret_cast<uint2*>(klo)[dst] = lo;
}

// ---------------------------------------------------------------------------
// V prep: [b,s,h,d] f32 -> transposed [b,h,d,s] bf16 hi + lo.
// Block = (b,h) x 64-row s-tile; LDS 64x68 transpose.
// ---------------------------------------------------------------------------
__global__ __launch_bounds__(256)
void v_prep(const float* __restrict__ vp, unsigned short* __restrict__ vthi,
            unsigned short* __restrict__ vtlo)
{
    __shared__ float lds[64][68];
    const int blk = blockIdx.x;
    const int bh = blk >> 4, s0 = (blk & 15) * 64;
    const int b = bh >> 3, h = bh & 7;
    const int t = threadIdx.x;
    {
        const int sl = t >> 4, d4 = t & 15;
        #pragma unroll
        for (int r = 0; r < 4; ++r) {
            const int s = sl + r * 16;
            const float4 v = reinterpret_cast<const float4*>(
                vp)[((long)(b * Lc + s0 + s) * Hc + h) * 16 + d4];
            *reinterpret_cast<float4*>(&lds[s][d4 * 4]) = v;
        }
    }
    __syncthreads();
    const int d = t >> 2, a = t & 3;
    #pragma unroll
    for (int jj = 0; jj < 4; ++jj) {
        const int sb = a * 16 + jj * 4;
        const float x0 = lds[sb + 0][d], x1 = lds[sb + 1][d];
        const float x2 = lds[sb + 2][d], x3 = lds[sb + 3][d];
        const unsigned short h0 = f2bf(x0), h1 = f2bf(x1), h2 = f2bf(x2), h3 = f2bf(x3);
        uint2 hi, lo;
        hi.x = (unsigned)h0 | ((unsigned)h1 << 16);
        hi.y = (unsigned)h2 | ((unsigned)h3 << 16);
        lo.x = (unsigned)f2bf(x0 - bf2f(h0)) | ((unsigned)f2bf(x1 - bf2f(h1)) << 16);
        lo.y = (unsigned)f2bf(x2 - bf2f(h2)) | ((unsigned)f2bf(x3 - bf2f(h3)) << 16);
        const long dst = (((long)bh * Dc + d) * Sc + s0 + sb) >> 2;  // uint2 units
        reinterpret_cast<uint2*>(vthi)[dst] = hi;
        reinterpret_cast<uint2*>(vtlo)[dst] = lo;
    }
}

// ---------------------------------------------------------------------------
// Fused attention + prior + sig.
// Block = (b,h) x 16 q-rows, 4 waves; wave w owns S-columns [w*256, w*256+256).
// QK^T via mfma_f32_16x16x32_bf16 (A-frag: lane l -> row l&15, k=(l>>4)*8+j;
// D: col=lane&15, row=(lane>>4)*4+reg). Scores in regs (16 x f32x4/lane),
// softmax without max-subtraction (|s*scale| <= ~6 -> exp safe in f32).
// P staged in LDS (per-wave [16][256] f32) -> coalesced series stores +
// PV A-frags. PV B-frags read V^T bf16 directly from L2. Cross-wave V
// reduction through LDS. Prior/sig fused at the end (pure writes).
// ---------------------------------------------------------------------------
__global__ __launch_bounds__(256, 2)
void attn_all(const float* __restrict__ qp,
              const unsigned short* __restrict__ khi,
              const unsigned short* __restrict__ klo,
              const unsigned short* __restrict__ vthi,
              const unsigned short* __restrict__ vtlo,
              const float* __restrict__ sigp, float* __restrict__ out)
{
    __shared__ float Plds[4][4096];     // per-wave [16][256] f32 (64 KB total)

    const int bid = blockIdx.x;
    const int swz = (bid & 7) * 256 + (bid >> 3);   // XCD-contiguous: 4 bh per XCD
    const int rowblk = swz & 63, bh = swz >> 6;
    const int b = bh >> 3, h = bh & 7;
    const int row0 = rowblk * 16;
    const int t = threadIdx.x;
    const int w = t >> 6;
    const int lane = t & 63;
    const int ln = lane & 15, kg = lane >> 4;
    float* const Pw = Plds[w];

    // ---- Q A-frags: read f32 directly, split to bf16 hi/lo (16 VGPRs) ----
    short8 qhi[2], qlo[2];
    {
        const float* qrow = qp + ((long)(b * Lc + row0 + ln) * Hc + h) * Ec;
        #pragma unroll
        for (int kc = 0; kc < 2; ++kc) {
            const float* qq = qrow + kc * 32 + kg * 8;
            const float4 qa = *reinterpret_cast<const float4*>(qq);
            const float4 qb = *reinterpret_cast<const float4*>(qq + 4);
            float qv[8] = {qa.x, qa.y, qa.z, qa.w, qb.x, qb.y, qb.z, qb.w};
            split8(qv, qhi[kc], qlo[kc]);
        }
    }

    // ---- QK^T: 16 col-tiles x (2 k-chunks x 3 split-terms) MFMA ----
    f32x4 p[16];
    const long kcb = (long)bh * Lc;
    #pragma unroll
    for (int tt = 0; tt < 16; ++tt) {
        const int col = w * 256 + tt * 16 + ln;
        const unsigned short* kb = khi + (kcb + col) * Ec + kg * 8;
        const unsigned short* kl = klo + (kcb + col) * Ec + kg * 8;
        const short8 bh0 = *reinterpret_cast<const short8*>(kb);
        const short8 bl0 = *reinterpret_cast<const short8*>(kl);
        const short8 bh1 = *reinterpret_cast<const short8*>(kb + 32);
        const short8 bl1 = *reinterpret_cast<const short8*>(kl + 32);
        f32x4 a = {0.f, 0.f, 0.f, 0.f};
        a = __builtin_amdgcn_mfma_f32_16x16x32_bf16(qhi[0], bh0, a, 0, 0, 0);
        a = __builtin_amdgcn_mfma_f32_16x16x32_bf16(qlo[0], bh0, a, 0, 0, 0);
        a = __builtin_amdgcn_mfma_f32_16x16x32_bf16(qhi[0], bl0, a, 0, 0, 0);
        a = __builtin_amdgcn_mfma_f32_16x16x32_bf16(qhi[1], bh1, a, 0, 0, 0);
        a = __builtin_amdgcn_mfma_f32_16x16x32_bf16(qlo[1], bh1, a, 0, 0, 0);
        a = __builtin_amdgcn_mfma_f32_16x16x32_bf16(qhi[1], bl1, a, 0, 0, 0);
        p[tt] = a;
    }

    // ---- softmax, no max pass: p = exp2(s_raw * 0.125 * log2e) ----
    const float C = 0.125f * LOG2E;
    float sl4[4] = {0.f, 0.f, 0.f, 0.f};
    #pragma unroll
    for (int tt = 0; tt < 16; ++tt) {
        #pragma unroll
        for (int i = 0; i < 4; ++i) {
            const float e = __builtin_exp2f(p[tt][i] * C);
            p[tt][i] = e; sl4[i] += e;
        }
    }
    #pragma unroll
    for (int off = 1; off < 16; off <<= 1) {
        #pragma unroll
        for (int i = 0; i < 4; ++i) sl4[i] += __shfl_xor(sl4[i], off, 64);
    }
    // cross-wave sum via Pw[0..15] (P not staged yet)
    if (ln == 0) {
        #pragma unroll
        for (int i = 0; i < 4; ++i) Pw[kg * 4 + i] = sl4[i];
    }
    __syncthreads();
    float inv[4];
    #pragma unroll
    for (int i = 0; i < 4; ++i) {
        const int rr = kg * 4 + i;
        inv[i] = 1.0f / (Plds[0][rr] + Plds[1][rr] + Plds[2][rr] + Plds[3][rr]);
    }
    __syncthreads();   // protect red slots until every wave has read them

    // ---- normalize -> stage P to LDS (row-major [16][256]) ----
    #pragma unroll
    for (int tt = 0; tt < 16; ++tt) {
        #pragma unroll
        for (int i = 0; i < 4; ++i) {
            const float v = p[tt][i] * inv[i];
            Pw[(kg * 4 + i) * 256 + tt * 16 + ln] = v;
        }
    }

    // ---- series store from LDS (coalesced dwordx4, 1 KB/instr) ----
    {
        const long sbase = OFF_SERIES + ((long)bh * Lc + row0) * Sc + w * 256;
        #pragma unroll
        for (int r = 0; r < 16; ++r) {
            const float4 v = *reinterpret_cast<const float4*>(&Pw[r * 256 + lane * 4]);
            *reinterpret_cast<float4*>(&out[sbase + (long)r * Sc + lane * 4]) = v;
        }
    }

    // ---- PV: A-frags from LDS P (f32 -> bf16 hi/lo), B-frags = V^T bf16 ----
    f32x4 acc2[4];
    #pragma unroll
    for (int dt = 0; dt < 4; ++dt) acc2[dt] = (f32x4){0.f, 0.f, 0.f, 0.f};
    #pragma unroll
    for (int kc = 0; kc < 8; ++kc) {
        const float* pa = &Pw[ln * 256 + kc * 32 + kg * 8];
        const float4 a0 = *reinterpret_cast<const float4*>(pa);
        const float4 a1 = *reinterpret_cast<const float4*>(pa + 4);
        float av[8] = {a0.x, a0.y, a0.z, a0.w, a1.x, a1.y, a1.z, a1.w};
        short8 phi, plo;
        split8(av, phi, plo);
        #pragma unroll
        for (int dt = 0; dt < 4; ++dt) {
            const long vb = ((long)bh * Dc + dt * 16 + ln) * Sc + w * 256 + kc * 32 + kg * 8;
            const short8 vh = *reinterpret_cast<const short8*>(vthi + vb);
            const short8 vl = *reinterpret_cast<const short8*>(vtlo + vb);
            acc2[dt] = __builtin_amdgcn_mfma_f32_16x16x32_bf16(phi, vh, acc2[dt], 0, 0, 0);
            acc2[dt] = __builtin_amdgcn_mfma_f32_16x16x32_bf16(plo, vh, acc2[dt], 0, 0, 0);
            acc2[dt] = __builtin_amdgcn_mfma_f32_16x16x32_bf16(phi, vl, acc2[dt], 0, 0, 0);
        }
    }

    // ---- cross-wave V reduction: partial into own Pw region (pitch 68) ----
    #pragma unroll
    for (int dt = 0; dt < 4; ++dt) {
        #pragma unroll
        for (int i = 0; i < 4; ++i)
            Pw[(kg * 4 + i) * 68 + dt * 16 + ln] = acc2[dt][i];
    }
    __syncthreads();
    {
        const int r = t >> 4, d0 = (t & 15) * 4;
        const float4 s0 = *reinterpret_cast<const float4*>(&Plds[0][r * 68 + d0]);
        const float4 s1 = *reinterpret_cast<const float4*>(&Plds[1][r * 68 + d0]);
        const float4 s2 = *reinterpret_cast<const float4*>(&Plds[2][r * 68 + d0]);
        const float4 s3 = *reinterpret_cast<const float4*>(&Plds[3][r * 68 + d0]);
        float4 vs;
        vs.x = s0.x + s1.x + s2.x + s3.x;
        vs.y = s0.y + s1.y + s2.y + s3.y;
        vs.z = s0.z + s1.z + s2.z + s3.z;
        vs.w = s0.w + s1.w + s2.w + s3.w;
        *reinterpret_cast<float4*>(
            &out[OFF_V + ((long)(b * Lc + row0 + r) * Hc + h) * Dc + d0]) = vs;
    }

    // ---- prior + sig (fused, pure writes) ----
    {
        const int c0 = t * 4;
        #pragma unroll 4
        for (int r = 0; r < 16; ++r) {
            const int lg = row0 + r;
            const float x = sigp[(long)(b * Lc + lg) * Hc + h];
            const float sgm = 1.0f / (1.0f + __builtin_exp2f(-FIVE_LOG2E * x)) + 1e-5f;
            const float sg = __builtin_exp2f(LOG2_3 * sgm) - 1.0f;
            const float amp = INV_SQRT_2PI / sg;
            const float ce = -HALF_LOG2E / (sg * sg);
            const long rowbase = ((long)bh * Lc + lg) * Sc;
            const float df = (float)(c0 - lg);
            float4 pr;
            pr.x = amp * __builtin_exp2f(ce * df * df);
            const float d1 = df + 1.f; pr.y = amp * __builtin_exp2f(ce * d1 * d1);
            const float d2 = df + 2.f; pr.z = amp * __builtin_exp2f(ce * d2 * d2);
            const float d3 = df + 3.f; pr.w = amp * __builtin_exp2f(ce * d3 * d3);
            *reinterpret_cast<float4*>(&out[OFF_PRIOR + rowbase + c0]) = pr;
            *reinterpret_cast<float4*>(&out[OFF_SIG + rowbase + c0]) =
                make_float4(sg, sg, sg, sg);
        }
    }
}

extern "C" void kernel_launch(void* const* d_in, const int* in_sizes, int n_in,
                              void* d_out, int out_size, void* d_ws, size_t ws_size,
                              hipStream_t stream) {
    const float* q  = (const float*)d_in[0];
    const float* k  = (const float*)d_in[1];
    const float* v  = (const float*)d_in[2];
    const float* sg = (const float*)d_in[3];
    float* out = (float*)d_out;

    // workspace: K_hi | K_lo | Vt_hi | Vt_lo  (4 x 4 MB bf16 = 16 MB)
    unsigned short* khi  = (unsigned short*)d_ws;
    unsigned short* klo  = khi + KELEMS;
    unsigned short* vthi = klo + KELEMS;
    unsigned short* vtlo = vthi + KELEMS;

    hipLaunchKernelGGL(k_prep, dim3(2048), dim3(256), 0, stream, k, khi, klo);
    hipLaunchKernelGGL(v_prep, dim3(512), dim3(256), 0, stream, v, vthi, vtlo);
    hipLaunchKernelGGL(attn_all, dim3(2048), dim3(256), 0, stream,
                       q, khi, klo, vthi, vtlo, sg, out);
}

// Round 4
// 553.095 us; speedup vs baseline: 1.0329x; 1.0329x over previous
//
#include <hip/hip_runtime.h>
#include <math.h>

// AnomalyAttention: B=4, H=8, L=S=1024, E=D=64, fp32 in/out.
// out = [ V (B,L,H,D) | series (B,H,L,S) | prior (B,H,L,S) | sig (B,H,L,S) ]
//
// No fp32 MFMA on CDNA4 -> 3-term split-bf16 MFMA (hi*hi + lo*hi + hi*lo,
// ~1e-4 rel err) for both QK^T and PV. Outputs = 411 MB -> ~65 us write floor.

typedef __attribute__((ext_vector_type(8))) short short8;   // 8 bf16 (4 VGPR)
typedef __attribute__((ext_vector_type(4))) float f32x4;

constexpr int Bc = 4, Lc = 1024, Hc = 8, Ec = 64, Dc = 64, Sc = 1024;

constexpr long OFF_V      = 0;
constexpr long OFF_SERIES = (long)Bc * Lc * Hc * Dc;                 // 2097152
constexpr long OFF_PRIOR  = OFF_SERIES + (long)Bc * Hc * Lc * Sc;    // 35651584
constexpr long OFF_SIG    = OFF_PRIOR  + (long)Bc * Hc * Lc * Sc;    // 69206016

constexpr long KELEMS = (long)Bc * Lc * Hc * Ec;   // 2097152 elements

#define LOG2E        1.4426950408889634f
#define LOG2_3       1.5849625007211562f
#define INV_SQRT_2PI 0.3989422804014327f
#define HALF_LOG2E   0.7213475204444817f
#define FIVE_LOG2E   7.213475204444817f

#define PPITCH 258   // f32 pitch of the per-wave P strip: writes land 2 lanes/bank (free)

__device__ __forceinline__ unsigned short f2bf(float x) {   // RTNE f32->bf16
    unsigned int u = __float_as_uint(x);
    return (unsigned short)((u + 0x7fffu + ((u >> 16) & 1u)) >> 16);
}
__device__ __forceinline__ float bf2f(unsigned short h) {
    return __uint_as_float(((unsigned int)h) << 16);
}
__device__ __forceinline__ void split8(const float* v, short8& hi, short8& lo) {
    #pragma unroll
    for (int j = 0; j < 8; ++j) {
        unsigned short hh = f2bf(v[j]);
        hi[j] = (short)hh;
        lo[j] = (short)f2bf(v[j] - bf2f(hh));
    }
}

// ---------------------------------------------------------------------------
// K prep: [b,s,h,e] f32 -> [b,h,s,e] bf16 hi + lo. 1 float4 per thread.
// ---------------------------------------------------------------------------
__global__ __launch_bounds__(256)
void k_prep(const float* __restrict__ kp, unsigned short* __restrict__ khi,
            unsigned short* __restrict__ klo)
{
    const int i = blockIdx.x * 256 + threadIdx.x;        // 0..524287
    const int e4 = i & 15, h = (i >> 4) & 7, s = (i >> 7) & 1023, b = i >> 17;
    const float4 v = reinterpret_cast<const float4*>(kp)[((b * Lc + s) * Hc + h) * 16 + e4];
    const unsigned short h0 = f2bf(v.x), h1 = f2bf(v.y), h2 = f2bf(v.z), h3 = f2bf(v.w);
    uint2 hi, lo;
    hi.x = (unsigned)h0 | ((unsigned)h1 << 16);
    hi.y = (unsigned)h2 | ((unsigned)h3 << 16);
    lo.x = (unsigned)f2bf(v.x - bf2f(h0)) | ((unsigned)f2bf(v.y - bf2f(h1)) << 16);
    lo.y = (unsigned)f2bf(v.z - bf2f(h2)) | ((unsigned)f2bf(v.w - bf2f(h3)) << 16);
    const long dst = ((long)(b * Hc + h) * Lc + s) * 16 + e4;   // uint2 units
    reinterpret_cast<uint2*>(khi)[dst] = hi;
    reinterpret_cast<uint2*>(klo)[dst] = lo;
}

// ---------------------------------------------------------------------------
// V prep: [b,s,h,d] f32 -> transposed [b,h,d,s] bf16 hi + lo.
// ---------------------------------------------------------------------------
__global__ __launch_bounds__(256)
void v_prep(const float* __restrict__ vp, unsigned short* __restrict__ vthi,
            unsigned short* __restrict__ vtlo)
{
    __shared__ float lds[64][68];
    const int blk = blockIdx.x;
    const int bh = blk >> 4, s0 = (blk & 15) * 64;
    const int b = bh >> 3, h = bh & 7;
    const int t = threadIdx.x;
    {
        const int sl = t >> 4, d4 = t & 15;
        #pragma unroll
        for (int r = 0; r < 4; ++r) {
            const int s = sl + r * 16;
            const float4 v = reinterpret_cast<const float4*>(
                vp)[((long)(b * Lc + s0 + s) * Hc + h) * 16 + d4];
            *reinterpret_cast<float4*>(&lds[s][d4 * 4]) = v;
        }
    }
    __syncthreads();
    const int d = t >> 2, a = t & 3;
    #pragma unroll
    for (int jj = 0; jj < 4; ++jj) {
        const int sb = a * 16 + jj * 4;
        const float x0 = lds[sb + 0][d], x1 = lds[sb + 1][d];
        const float x2 = lds[sb + 2][d], x3 = lds[sb + 3][d];
        const unsigned short h0 = f2bf(x0), h1 = f2bf(x1), h2 = f2bf(x2), h3 = f2bf(x3);
        uint2 hi, lo;
        hi.x = (unsigned)h0 | ((unsigned)h1 << 16);
        hi.y = (unsigned)h2 | ((unsigned)h3 << 16);
        lo.x = (unsigned)f2bf(x0 - bf2f(h0)) | ((unsigned)f2bf(x1 - bf2f(h1)) << 16);
        lo.y = (unsigned)f2bf(x2 - bf2f(h2)) | ((unsigned)f2bf(x3 - bf2f(h3)) << 16);
        const long dst = (((long)bh * Dc + d) * Sc + s0 + sb) >> 2;  // uint2 units
        reinterpret_cast<uint2*>(vthi)[dst] = hi;
        reinterpret_cast<uint2*>(vtlo)[dst] = lo;
    }
}

// ---------------------------------------------------------------------------
// Fused attention + prior + sig. Block = (b,h) x 16 q-rows, 4 waves; wave w
// owns S-columns [w*256, (w+1)*256).
//  - QK^T streamed: per 16-col tile -> 6 MFMA -> exp -> row-sum -> LDS write
//    (score regs stay at 4; normalization folded into later stages).
//  - PA fragments (P as bf16 hi/lo) built once into 64 VGPRs.
//  - PV dt-outer / kc-inner: per-wave live V^T line set = 4 KB -> L1-resident.
//  - Cross-wave V reduction via LDS; prior/sig fused tail (pure writes).
// ---------------------------------------------------------------------------
__global__ __launch_bounds__(256)
void attn_all(const float* __restrict__ qp,
              const unsigned short* __restrict__ khi,
              const unsigned short* __restrict__ klo,
              const unsigned short* __restrict__ vthi,
              const unsigned short* __restrict__ vtlo,
              const float* __restrict__ sigp, float* __restrict__ out)
{
    __shared__ float Pw_all[4][16 * PPITCH];   // 66 KB: per-wave P strip
    __shared__ float red[4][16];               // per-wave row sums

    const int bid = blockIdx.x;
    const int swz = (bid & 7) * 256 + (bid >> 3);   // XCD-contiguous: 4 bh per XCD
    const int rowblk = swz & 63, bh = swz >> 6;
    const int b = bh >> 3, h = bh & 7;
    const int row0 = rowblk * 16;
    const int t = threadIdx.x;
    const int w = t >> 6;
    const int lane = t & 63;
    const int ln = lane & 15, kg = lane >> 4;
    float* const Pw = Pw_all[w];

    // ---- Q A-frags: read f32, split to bf16 hi/lo (16 VGPRs) ----
    short8 qhi[2], qlo[2];
    {
        const float* qrow = qp + ((long)(b * Lc + row0 + ln) * Hc + h) * Ec;
        #pragma unroll
        for (int kc = 0; kc < 2; ++kc) {
            const float* qq = qrow + kc * 32 + kg * 8;
            const float4 qa = *reinterpret_cast<const float4*>(qq);
            const float4 qb = *reinterpret_cast<const float4*>(qq + 4);
            float qv[8] = {qa.x, qa.y, qa.z, qa.w, qb.x, qb.y, qb.z, qb.w};
            split8(qv, qhi[kc], qlo[kc]);
        }
    }

    // ---- QK^T streamed: 16 col-tiles, exp + sum + stage, 4 live score regs --
    const float C = 0.125f * LOG2E;
    float sl4[4] = {0.f, 0.f, 0.f, 0.f};
    const long kcb = (long)bh * Lc;
    #pragma unroll
    for (int tt = 0; tt < 16; ++tt) {
        const int col = w * 256 + tt * 16 + ln;
        const unsigned short* kb = khi + (kcb + col) * Ec + kg * 8;
        const unsigned short* kl = klo + (kcb + col) * Ec + kg * 8;
        const short8 bh0 = *reinterpret_cast<const short8*>(kb);
        const short8 bl0 = *reinterpret_cast<const short8*>(kl);
        const short8 bh1 = *reinterpret_cast<const short8*>(kb + 32);
        const short8 bl1 = *reinterpret_cast<const short8*>(kl + 32);
        f32x4 a = {0.f, 0.f, 0.f, 0.f};
        a = __builtin_amdgcn_mfma_f32_16x16x32_bf16(qhi[0], bh0, a, 0, 0, 0);
        a = __builtin_amdgcn_mfma_f32_16x16x32_bf16(qlo[0], bh0, a, 0, 0, 0);
        a = __builtin_amdgcn_mfma_f32_16x16x32_bf16(qhi[0], bl0, a, 0, 0, 0);
        a = __builtin_amdgcn_mfma_f32_16x16x32_bf16(qhi[1], bh1, a, 0, 0, 0);
        a = __builtin_amdgcn_mfma_f32_16x16x32_bf16(qlo[1], bh1, a, 0, 0, 0);
        a = __builtin_amdgcn_mfma_f32_16x16x32_bf16(qhi[1], bl1, a, 0, 0, 0);
        #pragma unroll
        for (int i = 0; i < 4; ++i) {
            const float e = __builtin_exp2f(a[i] * C);
            sl4[i] += e;
            Pw[(kg * 4 + i) * PPITCH + tt * 16 + ln] = e;   // 2 lanes/bank: free
        }
    }

    // ---- row sums: 16-lane group reduce, then cross-wave via red[] ----
    #pragma unroll
    for (int off = 1; off < 16; off <<= 1) {
        #pragma unroll
        for (int i = 0; i < 4; ++i) sl4[i] += __shfl_xor(sl4[i], off, 64);
    }
    if (ln == 0) {
        #pragma unroll
        for (int i = 0; i < 4; ++i) red[w][kg * 4 + i] = sl4[i];
    }
    __syncthreads();
    float inv4[4];   // per accumulator row r = kg*4+i (for PV epilogue)
    #pragma unroll
    for (int i = 0; i < 4; ++i) {
        const int rr = kg * 4 + i;
        inv4[i] = 1.0f / (red[0][rr] + red[1][rr] + red[2][rr] + red[3][rr]);
    }

    // ---- series store: normalize on the way out (coalesced b128 LDS reads) --
    {
        const long sbase = OFF_SERIES + ((long)bh * Lc + row0) * Sc + w * 256;
        #pragma unroll
        for (int r = 0; r < 16; ++r) {
            const float ivr = 1.0f / (red[0][r] + red[1][r] + red[2][r] + red[3][r]);
            float4 v = *reinterpret_cast<const float4*>(&Pw[r * PPITCH + lane * 4]);
            v.x *= ivr; v.y *= ivr; v.z *= ivr; v.w *= ivr;
            *reinterpret_cast<float4*>(&out[sbase + (long)r * Sc + lane * 4]) = v;
        }
    }

    // ---- PA fragments: unnormalized P -> bf16 hi/lo, once (64 VGPR) ----
    short8 pahi[8], palo[8];
    #pragma unroll
    for (int kc = 0; kc < 8; ++kc) {
        const float* pa = &Pw[ln * PPITCH + kc * 32 + kg * 8];
        const float4 a0 = *reinterpret_cast<const float4*>(pa);
        const float4 a1 = *reinterpret_cast<const float4*>(pa + 4);
        float av[8] = {a0.x, a0.y, a0.z, a0.w, a1.x, a1.y, a1.z, a1.w};
        split8(av, pahi[kc], palo[kc]);
    }

    // ---- PV: dt-outer (L1-friendly V^T streaming), 3-term split-bf16 ----
    #pragma unroll
    for (int dt = 0; dt < 4; ++dt) {
        f32x4 acc = {0.f, 0.f, 0.f, 0.f};
        const long vrow = ((long)bh * Dc + dt * 16 + ln) * Sc + w * 256 + kg * 8;
        #pragma unroll
        for (int kc = 0; kc < 8; ++kc) {
            const short8 vh = *reinterpret_cast<const short8*>(vthi + vrow + kc * 32);
            const short8 vl = *reinterpret_cast<const short8*>(vtlo + vrow + kc * 32);
            acc = __builtin_amdgcn_mfma_f32_16x16x32_bf16(pahi[kc], vh, acc, 0, 0, 0);
            acc = __builtin_amdgcn_mfma_f32_16x16x32_bf16(palo[kc], vh, acc, 0, 0, 0);
            acc = __builtin_amdgcn_mfma_f32_16x16x32_bf16(pahi[kc], vl, acc, 0, 0, 0);
        }
        // scaled partial into own wave's (now-free) P strip, pitch 68
        #pragma unroll
        for (int i = 0; i < 4; ++i)
            Pw[(kg * 4 + i) * 68 + dt * 16 + ln] = acc[i] * inv4[i];
    }
    __syncthreads();

    // ---- cross-wave V reduction + store ----
    {
        const int r = t >> 4, d0 = (t & 15) * 4;
        const float4 s0 = *reinterpret_cast<const float4*>(&Pw_all[0][r * 68 + d0]);
        const float4 s1 = *reinterpret_cast<const float4*>(&Pw_all[1][r * 68 + d0]);
        const float4 s2 = *reinterpret_cast<const float4*>(&Pw_all[2][r * 68 + d0]);
        const float4 s3 = *reinterpret_cast<const float4*>(&Pw_all[3][r * 68 + d0]);
        float4 vs;
        vs.x = s0.x + s1.x + s2.x + s3.x;
        vs.y = s0.y + s1.y + s2.y + s3.y;
        vs.z = s0.z + s1.z + s2.z + s3.z;
        vs.w = s0.w + s1.w + s2.w + s3.w;
        *reinterpret_cast<float4*>(
            &out[OFF_V + ((long)(b * Lc + row0 + r) * Hc + h) * Dc + d0]) = vs;
    }

    // ---- prior + sig (pure writes) ----
    {
        const int c0 = t * 4;
        #pragma unroll 4
        for (int r = 0; r < 16; ++r) {
            const int lg = row0 + r;
            const float x = sigp[(long)(b * Lc + lg) * Hc + h];
            const float sgm = 1.0f / (1.0f + __builtin_exp2f(-FIVE_LOG2E * x)) + 1e-5f;
            const float sg = __builtin_exp2f(LOG2_3 * sgm) - 1.0f;
            const float amp = INV_SQRT_2PI / sg;
            const float ce = -HALF_LOG2E / (sg * sg);
            const long rowbase = ((long)bh * Lc + lg) * Sc;
            const float df = (float)(c0 - lg);
            float4 pr;
            pr.x = amp * __builtin_exp2f(ce * df * df);
            const float d1 = df + 1.f; pr.y = amp * __builtin_exp2f(ce * d1 * d1);
            const float d2 = df + 2.f; pr.z = amp * __builtin_exp2f(ce * d2 * d2);
            const float d3 = df + 3.f; pr.w = amp * __builtin_exp2f(ce * d3 * d3);
            *reinterpret_cast<float4*>(&out[OFF_PRIOR + rowbase + c0]) = pr;
            *reinterpret_cast<float4*>(&out[OFF_SIG + rowbase + c0]) =
                make_float4(sg, sg, sg, sg);
        }
    }
}

extern "C" void kernel_launch(void* const* d_in, const int* in_sizes, int n_in,
                              void* d_out, int out_size, void* d_ws, size_t ws_size,
                              hipStream_t stream) {
    const float* q  = (const float*)d_in[0];
    const float* k  = (const float*)d_in[1];
    const float* v  = (const float*)d_in[2];
    const float* sg = (const float*)d_in[3];
    float* out = (float*)d_out;

    // workspace: K_hi | K_lo | Vt_hi | Vt_lo  (4 x 4 MB bf16 = 16 MB)
    unsigned short* khi  = (unsigned short*)d_ws;
    unsigned short* klo  = khi + KELEMS;
    unsigned short* vthi = klo + KELEMS;
    unsigned short* vtlo = vthi + KELEMS;

    hipLaunchKernelGGL(k_prep, dim3(2048), dim3(256), 0, stream, k, khi, klo);
    hipLaunchKernelGGL(v_prep, dim3(512), dim3(256), 0, stream, v, vthi, vtlo);
    hipLaunchKernelGGL(attn_all, dim3(2048), dim3(256), 0, stream,
                       q, khi, klo, vthi, vtlo, sg, out);
}